// Round 11
// baseline (2783.281 us; speedup 1.0000x reference)
//
#include <hip/hip_runtime.h>
#include <math.h>

#define BROWS 32768
#define DIM   1024
#define NLAT  64
#define NS    32
#define NL    256
#define RPB   32    // rows per block

// ---------------- prep kernel (proven by s_idx pass) ----------------

__global__ void prep_w2(const float* __restrict__ sq_w,
                        const float* __restrict__ sbank,
                        const float* __restrict__ sq_b,
                        double* __restrict__ W2d,
                        double* __restrict__ sconst)
{
    int t = blockIdx.x * blockDim.x + threadIdx.x;   // 32768 threads
    int s = t & (NS - 1);
    int d = t >> 5;
    const float* wr = sq_w + (size_t)d * DIM;
    const float* br = sbank + (size_t)s * DIM;
    double acc = 0.0;
    for (int o = 0; o < DIM; ++o) acc += (double)wr[o] * (double)br[o];
    W2d[(size_t)d * NS + s] = acc * 0.03125;
    if (d == 0) {
        double c = 0.0;
        for (int o = 0; o < DIM; ++o) c += (double)sq_b[o] * (double)br[o];
        sconst[s] = c * 0.03125;
    }
}

// ---------------- helpers ----------------

__device__ __forceinline__ void fma4(float4& A, float wgt, const float4& v) {
    A.x += wgt * v.x; A.y += wgt * v.y; A.z += wgt * v.z; A.w += wgt * v.w;
}

// numpy pairwise_sum SIMD base-case for a 128-block on AVX512 (nlanes=16):
// r_j = a[16j : 16j+16]; lanewise R = ((r0+r1)+(r2+r3)) + ((r4+r5)+(r6+r7));
// then _mm512_reduce_add_ps lane tree: (lo8+hi8) -> (lo4+hi4) -> (u0+u2)+(u1+u3).
__device__ __forceinline__ float np_simd128(const float* a) {
    float R[16];
#pragma unroll
    for (int l = 0; l < 16; ++l)
        R[l] = ((a[l] + a[l + 16]) + (a[l + 32] + a[l + 48]))
             + ((a[l + 64] + a[l + 80]) + (a[l + 96] + a[l + 112]));
    float t[8];
#pragma unroll
    for (int i = 0; i < 8; ++i) t[i] = R[i] + R[i + 8];
    float u[4];
#pragma unroll
    for (int i = 0; i < 4; ++i) u[i] = t[i] + t[i + 4];
    return (u[0] + u[2]) + (u[1] + u[3]);
}

// numpy SIMD f32 exp emulation (Cephes-derived poly, FMA Horner, rint quadrant).
__device__ __forceinline__ float np_expf(float x) {
    float m = rintf(x * 1.44269504088896341f);
    float r = fmaf(m, -0.693359375f, x);
    r = fmaf(m, 2.12194440e-4f, r);
    float y = 1.9875691500E-4f;
    y = fmaf(y, r, 1.3981999507E-3f);
    y = fmaf(y, r, 8.3334519073E-3f);
    y = fmaf(y, r, 4.1665795894E-2f);
    y = fmaf(y, r, 1.6666665459E-1f);
    y = fmaf(y, r, 5.0000001201E-1f);
    float r2 = r * r;
    y = fmaf(y, r2, r);
    y = y + 1.0f;
    return ldexpf(y, (int)m);
}

// ---------------- main fused kernel ----------------

__global__ __launch_bounds__(256, 2)
void hmb_main(const float* __restrict__ query,
              const float* __restrict__ qw,      // q_w (1024x64)
              const float* __restrict__ qb,      // q_b (64)
              const double* __restrict__ W2d,    // (1024x32) f64, pre-scaled
              const double* __restrict__ sconst, // (32) f64
              const float* __restrict__ lbank,   // (256x64)
              const float* __restrict__ dec_w,   // (64x1024)
              const float* __restrict__ dec_b,   // (1024)
              const float* __restrict__ sbank,   // (32x1024)
              float* __restrict__ out)
{
    __shared__ __align__(16) unsigned char raw[45248];
    // phase A (long, f32) regions:
    float  (*QsC)[64]  = (float  (*)[64])(raw);            // [    0,  8192)
    float  (*LqF)[64]  = (float  (*)[64])(raw + 8192);     // [ 8192, 16384)
    float  *ScF        = (float  *)(raw + 16384);          // [16384, 17408)
    float  *EfF        = (float  *)(raw + 17408);          // [17408, 18432)
    float  *VfF        = (float  *)(raw + 18432);          // [18432, 19456)
    // phase B (short, f64) reuses [0, 21760):
    float  (*Qs)[36]   = (float  (*)[36])(raw);            // [    0,  4608)
    double (*W2cT)[34] = (double (*)[34])(raw + 4608);     // [ 4608, 13312)
    double (*Pl)[33]   = (double (*)[33])(raw + 13312);    // [13312, 21760)
    // phase 3 reuses [0, 33280):
    float  (*Wd)[260]  = (float  (*)[260])(raw);
    // survivors (>= 33280, untouched by Wd):
    float  (*Zl)[68]   = (float  (*)[68])(raw + 33280);    // [33280, 41984)
    int    (*SWi)[4]   = (int    (*)[4])(raw + 41984);     // [41984, 42496)
    float  (*SWv)[4]   = (float  (*)[4])(raw + 42496);     // [42496, 43008)
    float  *SLT        = (float  *)(raw + 43008);          // [43008, 43136)
    int    (*LWiA)[8]  = (int    (*)[8])(raw + 43136);     // [43136, 44160)
    float  (*LtvA)[8]  = (float  (*)[8])(raw + 44160);     // [44160, 45184)
    float  *mrow       = (float  *)(raw + 45184);
    float  *srow       = (float  *)(raw + 45188);

    const int t    = threadIdx.x;
    const int tc   = t & 15;
    const int tr   = t >> 4;
    const int lane = t & 63;
    const int wv   = t >> 6;
    const int j64  = t & 63;
    const int rowg = t >> 6;
    const int row0 = blockIdx.x * RPB;

    const size_t OS_SIDX = 33554432ull;
    const size_t OS_LIDX = 33685504ull;
    const size_t OS_STOP = 33947648ull;
    const size_t OS_LTOP = 34078720ull;

    // ============ phase A1: lq in f32, OpenBLAS Zen/Haswell KC=384 panel emulation ====
    // C = (((p[0,384) + p[384,768)) + p[768,1024))) + q_b
    {
        float la[8] = {0, 0, 0, 0, 0, 0, 0, 0};   // current panel chain
        float lt[8] = {0, 0, 0, 0, 0, 0, 0, 0};   // committed C
#pragma unroll 1
        for (int c = 0; c < 16; ++c) {
            if (c == 6 || c == 12) {              // panel boundary at k=384, 768
#pragma unroll
                for (int i = 0; i < 8; ++i) { lt[i] += la[i]; la[i] = 0.0f; }
            }
            __syncthreads();   // QsC readers of previous chunk done
#pragma unroll
            for (int ii = 0; ii < 2; ++ii) {
                int e = t + 256 * ii;          // 0..511
                int rr = e >> 4, f4 = e & 15;
                *(float4*)&QsC[rr][4 * f4] =
                    *(const float4*)(query + (size_t)(row0 + rr) * DIM + c * 64 + 4 * f4);
            }
            __syncthreads();
#pragma unroll 4
            for (int dd = 0; dd < 64; ++dd) {
                float wl = qw[(size_t)(c * 64 + dd) * NLAT + j64];
#pragma unroll
                for (int i = 0; i < 8; ++i)
                    la[i] = fmaf(QsC[rowg * 8 + i][dd], wl, la[i]);
            }
        }
        __syncthreads();
#pragma unroll
        for (int i = 0; i < 8; ++i)
            LqF[rowg * 8 + i][j64] = (lt[i] + la[i]) + qb[j64];   // final panel add, then bias
        __syncthreads();
    }

    // ============ phase A2: per-row f32 scores / np-softmax / top-8 / z ============
#pragma unroll 1
    for (int row = 0; row < 32; ++row) {
        // (a) logits: sequential FMA j=0..63 (k=64 < KC: single panel), then *0.125f
        {
            float sc = 0.0f;
            const float* lbr = lbank + (size_t)t * NLAT;   // thread t owns slot t
#pragma unroll
            for (int j = 0; j < NLAT; ++j)
                sc = fmaf(LqF[row][j], lbr[j], sc);
            ScF[t] = sc * 0.125f;
        }
        __syncthreads();
        // (b) f32 max (exact, order-independent)
        if (t == 0) {
            float m = ScF[0];
            for (int l = 1; l < NL; ++l) m = fmaxf(m, ScF[l]);
            *mrow = m;
        }
        __syncthreads();
        // (c) e = np_expf(x - m)
        EfF[t] = np_expf(ScF[t] - *mrow);
        __syncthreads();
        // (d) denominator: numpy pairwise sum, AVX512 SIMD base-case (256 = 128 + 128)
        if (t == 0) *srow = np_simd128(EfF) + np_simd128(EfF + 128);
        __syncthreads();
        // (e) values
        VfF[t] = EfF[t] / *srow;
        __syncthreads();
        // (f) top-8 insertion on f32 values — strict ">": stable lower-index-first
        if (t == 0) {
            float v0=-1.0e30f,v1=-1.0e30f,v2=-1.0e30f,v3=-1.0e30f,
                  v4=-1.0e30f,v5=-1.0e30f,v6=-1.0e30f,v7=-1.0e30f;
            int j0=0,j1=0,j2=0,j3=0,j4=0,j5=0,j6=0,j7=0;
            for (int l = 0; l < NL; ++l) {
                float v = VfF[l];
                if (v > v7) {
                    if (v > v3) {
                        if (v > v1) {
                            if (v > v0) { v7=v6;j7=j6; v6=v5;j6=j5; v5=v4;j5=j4; v4=v3;j4=j3; v3=v2;j3=j2; v2=v1;j2=j1; v1=v0;j1=j0; v0=v;j0=l; }
                            else        { v7=v6;j7=j6; v6=v5;j6=j5; v5=v4;j5=j4; v4=v3;j4=j3; v3=v2;j3=j2; v2=v1;j2=j1; v1=v;j1=l; }
                        } else {
                            if (v > v2) { v7=v6;j7=j6; v6=v5;j6=j5; v5=v4;j5=j4; v4=v3;j4=j3; v3=v2;j3=j2; v2=v;j2=l; }
                            else        { v7=v6;j7=j6; v6=v5;j6=j5; v5=v4;j5=j4; v4=v3;j4=j3; v3=v;j3=l; }
                        }
                    } else {
                        if (v > v5) {
                            if (v > v4) { v7=v6;j7=j6; v6=v5;j6=j5; v5=v4;j5=j4; v4=v;j4=l; }
                            else        { v7=v6;j7=j6; v6=v5;j6=j5; v5=v;j5=l; }
                        } else {
                            if (v > v6) { v7=v6;j7=j6; v6=v;j6=l; }
                            else        { v7=v;j7=l; }
                        }
                    }
                }
            }
            LWiA[row][0]=j0; LWiA[row][1]=j1; LWiA[row][2]=j2; LWiA[row][3]=j3;
            LWiA[row][4]=j4; LWiA[row][5]=j5; LWiA[row][6]=j6; LWiA[row][7]=j7;
            LtvA[row][0]=v0; LtvA[row][1]=v1; LtvA[row][2]=v2; LtvA[row][3]=v3;
            LtvA[row][4]=v4; LtvA[row][5]=v5; LtvA[row][6]=v6; LtvA[row][7]=v7;
            SLT[row] = v0+v1+v2+v3+v4+v5+v6+v7;
        }
        __syncthreads();
        // (g) z_j = sum_k v_k * lbank[idx_k][j];  (h) l_idx / l_top outputs
        if (t < 64) {
            float zv = 0.0f;
#pragma unroll
            for (int k = 0; k < 8; ++k)
                zv += LtvA[row][k] * lbank[(size_t)LWiA[row][k] * NLAT + t];
            Zl[row][t] = zv;
        } else if (t == 64) {
            size_t grow = (size_t)(row0 + row);
            float* pi = out + OS_LIDX + grow * 8;
            float* pt = out + OS_LTOP + grow * 8;
#pragma unroll
            for (int k = 0; k < 8; ++k) { pi[k] = (float)LWiA[row][k]; pt[k] = LtvA[row][k]; }
        }
        __syncthreads();
    }

    // ============ phase B1: short logits in f64 (verbatim, passing) ============
    {
        double a00 = 0, a01 = 0, a10 = 0, a11 = 0;
#pragma unroll 1
        for (int ci = 0; ci < 32; ++ci) {
            const int d0 = ci * 32;
            {   // stage Q tile chunk (32 rows x 32 d)
                int r = t >> 3, f4 = t & 7;
                float4 v = *(const float4*)(query + (size_t)(row0 + r) * DIM + d0 + 4 * f4);
                *(float4*)&Qs[r][4 * f4] = v;
            }
            {   // stage W2 chunk, transposed to [s][dd]
                const double2* src = (const double2*)(W2d + (size_t)d0 * NS);
                double2 v0 = src[2 * t], v1 = src[2 * t + 1];
                int i0 = 4 * t;
                W2cT[(i0)     & 31][(i0)     >> 5] = v0.x;
                W2cT[(i0 + 1) & 31][(i0 + 1) >> 5] = v0.y;
                W2cT[(i0 + 2) & 31][(i0 + 2) >> 5] = v1.x;
                W2cT[(i0 + 3) & 31][(i0 + 3) >> 5] = v1.y;
            }
            __syncthreads();
#pragma unroll
            for (int dd = 0; dd < 32; dd += 2) {
                float2 qa = *(const float2*)&Qs[tr][dd];
                float2 qc = *(const float2*)&Qs[tr + 16][dd];
                double q00 = qa.x, q01 = qa.y, q10 = qc.x, q11 = qc.y;
                double2 w0 = *(const double2*)&W2cT[tc][dd];
                a00 += q00 * w0.x + q01 * w0.y;
                a10 += q10 * w0.x + q11 * w0.y;
                double2 w1 = *(const double2*)&W2cT[tc + 16][dd];
                a01 += q00 * w1.x + q01 * w1.y;
                a11 += q10 * w1.x + q11 * w1.y;
            }
            __syncthreads();
        }
        {
            double c0 = sconst[tc], c1 = sconst[tc + 16];
            Pl[tc][tr]           = a00 + c0;
            Pl[tc][tr + 16]      = a10 + c0;
            Pl[tc + 16][tr]      = a01 + c1;
            Pl[tc + 16][tr + 16] = a11 + c1;
        }
        __syncthreads();
    }

    // ============ phase B2: short top-4 butterfly (verbatim, passing) ============
#pragma unroll 1
    for (int rg = 0; rg < 8; ++rg) {
        const int r = 8 * wv + rg;
        const size_t grow = (size_t)(row0 + r);

        double sx0 = (lane < NS) ? Pl[lane][r] : -1.0e300;
        double sx = sx0;
        double swv_[4]; int swi_[4];
#pragma unroll
        for (int it = 0; it < 4; ++it) {
            double v = sx; int ix = lane;
#pragma unroll
            for (int off = 32; off > 0; off >>= 1) {
                double ov = __shfl_xor(v, off, 64);
                int oi = __shfl_xor(ix, off, 64);
                if (ov > v || (ov == v && oi < ix)) { v = ov; ix = oi; }
            }
            swv_[it] = v; swi_[it] = ix;
            if (lane == ix) sx = -1.0e300;
        }
        double sm = swv_[0];
        double ssum = (lane < NS) ? (double)expf((float)(sx0 - sm)) : 0.0;
#pragma unroll
        for (int off = 32; off > 0; off >>= 1) ssum += __shfl_xor(ssum, off, 64);
        float stv[4];
#pragma unroll
        for (int it = 0; it < 4; ++it)
            stv[it] = (float)((double)expf((float)(swv_[it] - sm)) / ssum);

        if (lane == 0) {
#pragma unroll
            for (int k = 0; k < 4; ++k) { SWi[r][k] = swi_[k]; SWv[r][k] = stv[k]; }
            float* ps = out + OS_SIDX + grow * 4;
            float* pt = out + OS_STOP + grow * 4;
#pragma unroll
            for (int k = 0; k < 4; ++k) { ps[k] = (float)swi_[k]; pt[k] = stv[k]; }
        }
    }
    __syncthreads();

    // ============ phase 3: retrieved = short-gather + Z @ dec_w + SLT*dec_b ========
    const int rgrp = t >> 6;
    const int col4 = t & 63;

#pragma unroll 1
    for (int dc = 0; dc < 4; ++dc) {
        const int cbase = dc * 256 + 4 * col4;
        float4 acc[8];
#pragma unroll
        for (int r8 = 0; r8 < 8; ++r8) {
            const int row = rgrp * 8 + r8;
            float slt = SLT[row];
            float4 db = *(const float4*)(dec_b + cbase);
            float4 a;
            a.x = slt * db.x; a.y = slt * db.y; a.z = slt * db.z; a.w = slt * db.w;
#pragma unroll
            for (int k = 0; k < 4; ++k) {
                int   si = SWi[row][k];
                float sv = SWv[row][k];
                float4 sb = *(const float4*)(sbank + (size_t)si * DIM + cbase);
                fma4(a, sv, sb);
            }
            acc[r8] = a;
        }
#pragma unroll 1
        for (int jh = 0; jh < 2; ++jh) {
            __syncthreads();   // prior Wd/Pl readers done before restage
#pragma unroll
            for (int i = 0; i < 8; ++i) {
                int e = t + 256 * i;
                int jr = e >> 6, c4 = e & 63;
                *(float4*)&Wd[jr][4 * c4] =
                    *(const float4*)(dec_w + (size_t)(32 * jh + jr) * DIM + dc * 256 + 4 * c4);
            }
            __syncthreads();
#pragma unroll 4
            for (int j2 = 0; j2 < 32; ++j2) {
                float4 wv4 = *(const float4*)&Wd[j2][4 * col4];
#pragma unroll
                for (int r8 = 0; r8 < 8; ++r8) {
                    float z = Zl[rgrp * 8 + r8][32 * jh + j2];
                    fma4(acc[r8], z, wv4);
                }
            }
        }
#pragma unroll
        for (int r8 = 0; r8 < 8; ++r8) {
            const int row = rgrp * 8 + r8;
            *(float4*)(out + (size_t)(row0 + row) * DIM + cbase) = acc[r8];
        }
    }
}

// ---------------- launcher ----------------

extern "C" void kernel_launch(void* const* d_in, const int* in_sizes, int n_in,
                              void* d_out, int out_size, void* d_ws, size_t ws_size,
                              hipStream_t stream) {
    const float* query = (const float*)d_in[0];
    const float* sbank = (const float*)d_in[1];
    const float* lbank = (const float*)d_in[2];
    const float* dec_w = (const float*)d_in[3];
    const float* dec_b = (const float*)d_in[4];
    const float* q_w   = (const float*)d_in[5];
    const float* q_b   = (const float*)d_in[6];
    const float* sq_w  = (const float*)d_in[7];
    const float* sq_b  = (const float*)d_in[8];
    float* out = (float*)d_out;

    char* ws = (char*)d_ws;
    double* W2d    = (double*)(ws);             // [0, 262144)
    double* sconst = (double*)(ws + 262144);    // [262144, 262400)

    prep_w2 <<<dim3(128), dim3(256), 0, stream>>>(sq_w, sbank, sq_b, W2d, sconst);
    hmb_main<<<dim3(BROWS / RPB), dim3(256), 0, stream>>>(
        query, q_w, q_b, W2d, sconst, lbank, dec_w, dec_b, sbank, out);
}

// Round 12
// 688.048 us; speedup vs baseline: 4.0452x; 4.0452x over previous
//
#include <hip/hip_runtime.h>
#include <math.h>

#define BROWS 32768
#define DIM   1024
#define NLAT  64
#define NS    32
#define NL    256
#define RPB   32    // rows per block

// ---------------- prep kernel (proven) ----------------

__global__ void prep_w2(const float* __restrict__ sq_w,
                        const float* __restrict__ sbank,
                        const float* __restrict__ sq_b,
                        double* __restrict__ W2d,
                        double* __restrict__ sconst)
{
    int t = blockIdx.x * blockDim.x + threadIdx.x;   // 32768 threads
    int s = t & (NS - 1);
    int d = t >> 5;
    const float* wr = sq_w + (size_t)d * DIM;
    const float* br = sbank + (size_t)s * DIM;
    double acc = 0.0;
    for (int o = 0; o < DIM; ++o) acc += (double)wr[o] * (double)br[o];
    W2d[(size_t)d * NS + s] = acc * 0.03125;
    if (d == 0) {
        double c = 0.0;
        for (int o = 0; o < DIM; ++o) c += (double)sq_b[o] * (double)br[o];
        sconst[s] = c * 0.03125;
    }
}

// ---------------- helpers ----------------

__device__ __forceinline__ void fma4(float4& A, float wgt, const float4& v) {
    A.x += wgt * v.x; A.y += wgt * v.y; A.z += wgt * v.z; A.w += wgt * v.w;
}

// numpy SIMD f32 exp emulation (Cephes-derived poly, FMA Horner, rint quadrant).
__device__ __forceinline__ float np_expf(float x) {
    float m = rintf(x * 1.44269504088896341f);
    float r = fmaf(m, -0.693359375f, x);
    r = fmaf(m, 2.12194440e-4f, r);
    float y = 1.9875691500E-4f;
    y = fmaf(y, r, 1.3981999507E-3f);
    y = fmaf(y, r, 8.3334519073E-3f);
    y = fmaf(y, r, 4.1665795894E-2f);
    y = fmaf(y, r, 1.6666665459E-1f);
    y = fmaf(y, r, 5.0000001201E-1f);
    float r2 = r * r;
    y = fmaf(y, r2, r);
    y = y + 1.0f;
    return ldexpf(y, (int)m);
}

// ---------------- main fused kernel ----------------

__global__ __launch_bounds__(256, 3)
void hmb_main(const float* __restrict__ query,
              const float* __restrict__ qw,      // q_w (1024x64)
              const float* __restrict__ qb,      // q_b (64)
              const double* __restrict__ W2d,    // (1024x32) f64, pre-scaled
              const double* __restrict__ sconst, // (32) f64
              const float* __restrict__ lbank,   // (256x64)
              const float* __restrict__ dec_w,   // (64x1024)
              const float* __restrict__ dec_b,   // (1024)
              const float* __restrict__ sbank,   // (32x1024)
              float* __restrict__ out)
{
    __shared__ __align__(16) unsigned char raw[50816];
    // phase A regions:
    float  (*LqF)[64]  = (float  (*)[64])(raw);            // [    0,  8192)
    float  (*Sc)[256]  = (float  (*)[256])(raw + 8192);    // [ 8192, 40960)
    // phase B (short, f64) reuses [0, 21760):
    float  (*Qs)[36]   = (float  (*)[36])(raw);            // [    0,  4608)
    double (*W2cT)[34] = (double (*)[34])(raw + 4608);     // [ 4608, 13312)
    double (*Pl)[33]   = (double (*)[33])(raw + 13312);    // [13312, 21760)
    // phase 3 reuses [0, 33280):
    float  (*Wd)[260]  = (float  (*)[260])(raw);
    // survivors (>= 40960):
    float  (*Zl)[68]   = (float  (*)[68])(raw + 40960);    // [40960, 49664)
    int    (*SWi)[4]   = (int    (*)[4])(raw + 49664);     // [49664, 50176)
    float  (*SWv)[4]   = (float  (*)[4])(raw + 50176);     // [50176, 50688)
    float  *SLT        = (float  *)(raw + 50688);          // [50688, 50816)

    const int t    = threadIdx.x;
    const int tc   = t & 15;
    const int tr   = t >> 4;
    const int lane = t & 63;
    const int wv   = t >> 6;
    const int row0 = blockIdx.x * RPB;

    const size_t OS_SIDX = 33554432ull;
    const size_t OS_LIDX = 33685504ull;
    const size_t OS_STOP = 33947648ull;
    const size_t OS_LTOP = 34078720ull;

    // ============ phase A1: lq f32, KC=384 panels, broadcast q reads (no barriers) ====
    {
        const float* qrow = query + (size_t)(row0 + 8 * wv) * DIM;
        float lt[8] = {0, 0, 0, 0, 0, 0, 0, 0};
#pragma unroll 1
        for (int s = 0; s < 3; ++s) {
            const int dlo = s * 384;
            const int dhi = (s == 2) ? 1024 : (dlo + 384);
            float la[8] = {0, 0, 0, 0, 0, 0, 0, 0};
#pragma unroll 4
            for (int d = dlo; d < dhi; ++d) {
                float wl = qw[(size_t)d * NLAT + lane];
#pragma unroll
                for (int i = 0; i < 8; ++i)
                    la[i] = fmaf(qrow[(size_t)i * DIM + d], wl, la[i]);
            }
#pragma unroll
            for (int i = 0; i < 8; ++i) lt[i] += la[i];   // panel commits: ((p0+p1)+p2)
        }
#pragma unroll
        for (int i = 0; i < 8; ++i)
            LqF[8 * wv + i][lane] = lt[i] + qb[lane];
    }
    __syncthreads();

    // ============ phase A2a: scores, slot-per-thread, all 32 rows at once ============
    {
        float acc[32];
#pragma unroll
        for (int rr = 0; rr < 32; ++rr) acc[rr] = 0.0f;
        const float4* lb4 = (const float4*)(lbank + (size_t)t * NLAT);
#pragma unroll 1
        for (int jq = 0; jq < 16; ++jq) {
            float4 b = lb4[jq];
#pragma unroll
            for (int rr = 0; rr < 32; ++rr) {
                float4 q4 = *(const float4*)&LqF[rr][4 * jq];
                float a = acc[rr];
                a = fmaf(q4.x, b.x, a);
                a = fmaf(q4.y, b.y, a);
                a = fmaf(q4.z, b.z, a);
                a = fmaf(q4.w, b.w, a);
                acc[rr] = a;
            }
        }
#pragma unroll
        for (int rr = 0; rr < 32; ++rr) Sc[rr][t] = acc[rr] * 0.125f;
    }
    __syncthreads();

    // ============ phase A2b: wave-parallel softmax / top-8 / z (no barriers) =========
#pragma unroll 1
    for (int rg = 0; rg < 8; ++rg) {
        const int row = 8 * wv + rg;
        const size_t grow = (size_t)(row0 + row);
        float c0 = Sc[row][lane],       c1 = Sc[row][lane + 64],
              c2 = Sc[row][lane + 128], c3 = Sc[row][lane + 192];
        // max (order-independent, bitwise == serial scan)
        float m = fmaxf(fmaxf(c0, c1), fmaxf(c2, c3));
#pragma unroll
        for (int off = 32; off > 0; off >>= 1)
            m = fmaxf(m, __shfl_xor(m, off, 64));
        float e0 = np_expf(c0 - m), e1 = np_expf(c1 - m),
              e2 = np_expf(c2 - m), e3 = np_expf(c3 - m);
        // denominator: exact numpy AVX512 pairwise tree via shuffles
        float A0 = e0 + __shfl_down(e0, 16, 64);
        float B0 = __shfl_down(e0, 32, 64) + __shfl_down(e0, 48, 64);
        float C0 = e1 + __shfl_down(e1, 16, 64);
        float D0 = __shfl_down(e1, 32, 64) + __shfl_down(e1, 48, 64);
        float R0 = (A0 + B0) + (C0 + D0);                 // lanes 0..15: R[l], block 0
        float A1_ = e2 + __shfl_down(e2, 16, 64);
        float B1_ = __shfl_down(e2, 32, 64) + __shfl_down(e2, 48, 64);
        float C1_ = e3 + __shfl_down(e3, 16, 64);
        float D1_ = __shfl_down(e3, 32, 64) + __shfl_down(e3, 48, 64);
        float R1 = (A1_ + B1_) + (C1_ + D1_);             // lanes 0..15: R[l], block 1
        float t0 = R0 + __shfl_down(R0, 8, 64);
        float u0 = t0 + __shfl_down(t0, 4, 64);
        float f0 = (u0 + __shfl_down(u0, 2, 64)) + (__shfl_down(u0, 1, 64) + __shfl_down(u0, 3, 64));
        float t1 = R1 + __shfl_down(R1, 8, 64);
        float u1 = t1 + __shfl_down(t1, 4, 64);
        float f1 = (u1 + __shfl_down(u1, 2, 64)) + (__shfl_down(u1, 1, 64) + __shfl_down(u1, 3, 64));
        float sden = __shfl(f0 + f1, 0, 64);
        float v0 = e0 / sden, v1 = e1 / sden, v2 = e2 / sden, v3 = e3 / sden;
        // top-8 butterfly: strict > , lowest index on ties (== stable insertion)
        float ltv[8]; int lwi[8];
#pragma unroll
        for (int it = 0; it < 8; ++it) {
            float v = v0; int u = 0;
            if (v1 > v) { v = v1; u = 1; }
            if (v2 > v) { v = v2; u = 2; }
            if (v3 > v) { v = v3; u = 3; }
            int gi = lane + (u << 6);
#pragma unroll
            for (int off = 32; off > 0; off >>= 1) {
                float ov = __shfl_xor(v, off, 64);
                int og = __shfl_xor(gi, off, 64);
                if (ov > v || (ov == v && og < gi)) { v = ov; gi = og; }
            }
            ltv[it] = v; lwi[it] = gi;
            if ((gi & 63) == lane) {
                int wu = gi >> 6;
                if      (wu == 0) v0 = -1.0e30f;
                else if (wu == 1) v1 = -1.0e30f;
                else if (wu == 2) v2 = -1.0e30f;
                else              v3 = -1.0e30f;
            }
        }
        // z_j = sum_k v_k * lbank[idx_k][j]
        float zv = 0.0f;
#pragma unroll
        for (int k = 0; k < 8; ++k)
            zv += ltv[k] * lbank[(size_t)lwi[k] * NLAT + lane];
        Zl[row][lane] = zv;
        if (lane == 0) {
            SLT[row] = ltv[0]+ltv[1]+ltv[2]+ltv[3]+ltv[4]+ltv[5]+ltv[6]+ltv[7];
        } else if (lane == 1) {
            float* pi = out + OS_LIDX + grow * 8;
            float* pt = out + OS_LTOP + grow * 8;
#pragma unroll
            for (int k = 0; k < 8; ++k) { pi[k] = (float)lwi[k]; pt[k] = ltv[k]; }
        }
    }
    __syncthreads();   // Sc/LqF dead; phase B may overwrite region

    // ============ phase B1: short logits in f64 (verbatim, passing) ============
    {
        double a00 = 0, a01 = 0, a10 = 0, a11 = 0;
#pragma unroll 1
        for (int ci = 0; ci < 32; ++ci) {
            const int d0 = ci * 32;
            {   // stage Q tile chunk (32 rows x 32 d)
                int r = t >> 3, f4i = t & 7;
                float4 v = *(const float4*)(query + (size_t)(row0 + r) * DIM + d0 + 4 * f4i);
                *(float4*)&Qs[r][4 * f4i] = v;
            }
            {   // stage W2 chunk, transposed to [s][dd]
                const double2* src = (const double2*)(W2d + (size_t)d0 * NS);
                double2 v0 = src[2 * t], v1 = src[2 * t + 1];
                int i0 = 4 * t;
                W2cT[(i0)     & 31][(i0)     >> 5] = v0.x;
                W2cT[(i0 + 1) & 31][(i0 + 1) >> 5] = v0.y;
                W2cT[(i0 + 2) & 31][(i0 + 2) >> 5] = v1.x;
                W2cT[(i0 + 3) & 31][(i0 + 3) >> 5] = v1.y;
            }
            __syncthreads();
#pragma unroll
            for (int dd = 0; dd < 32; dd += 2) {
                float2 qa = *(const float2*)&Qs[tr][dd];
                float2 qc = *(const float2*)&Qs[tr + 16][dd];
                double q00 = qa.x, q01 = qa.y, q10 = qc.x, q11 = qc.y;
                double2 w0 = *(const double2*)&W2cT[tc][dd];
                a00 += q00 * w0.x + q01 * w0.y;
                a10 += q10 * w0.x + q11 * w0.y;
                double2 w1 = *(const double2*)&W2cT[tc + 16][dd];
                a01 += q00 * w1.x + q01 * w1.y;
                a11 += q10 * w1.x + q11 * w1.y;
            }
            __syncthreads();
        }
        {
            double c0 = sconst[tc], c1 = sconst[tc + 16];
            Pl[tc][tr]           = a00 + c0;
            Pl[tc][tr + 16]      = a10 + c0;
            Pl[tc + 16][tr]      = a01 + c1;
            Pl[tc + 16][tr + 16] = a11 + c1;
        }
        __syncthreads();
    }

    // ============ phase B2: short top-4 butterfly (verbatim, passing) ============
#pragma unroll 1
    for (int rg = 0; rg < 8; ++rg) {
        const int r = 8 * wv + rg;
        const size_t grow = (size_t)(row0 + r);

        double sx0 = (lane < NS) ? Pl[lane][r] : -1.0e300;
        double sx = sx0;
        double swv_[4]; int swi_[4];
#pragma unroll
        for (int it = 0; it < 4; ++it) {
            double v = sx; int ix = lane;
#pragma unroll
            for (int off = 32; off > 0; off >>= 1) {
                double ov = __shfl_xor(v, off, 64);
                int oi = __shfl_xor(ix, off, 64);
                if (ov > v || (ov == v && oi < ix)) { v = ov; ix = oi; }
            }
            swv_[it] = v; swi_[it] = ix;
            if (lane == ix) sx = -1.0e300;
        }
        double sm = swv_[0];
        double ssum = (lane < NS) ? (double)expf((float)(sx0 - sm)) : 0.0;
#pragma unroll
        for (int off = 32; off > 0; off >>= 1) ssum += __shfl_xor(ssum, off, 64);
        float stv[4];
#pragma unroll
        for (int it = 0; it < 4; ++it)
            stv[it] = (float)((double)expf((float)(swv_[it] - sm)) / ssum);

        if (lane == 0) {
#pragma unroll
            for (int k = 0; k < 4; ++k) { SWi[r][k] = swi_[k]; SWv[r][k] = stv[k]; }
            float* ps = out + OS_SIDX + grow * 4;
            float* pt = out + OS_STOP + grow * 4;
#pragma unroll
            for (int k = 0; k < 4; ++k) { ps[k] = (float)swi_[k]; pt[k] = stv[k]; }
        }
    }
    __syncthreads();

    // ============ phase 3: retrieved = short-gather + Z @ dec_w + SLT*dec_b ========
    const int rgrp = t >> 6;
    const int col4 = t & 63;

#pragma unroll 1
    for (int dc = 0; dc < 4; ++dc) {
        const int cbase = dc * 256 + 4 * col4;
        float4 acc[8];
#pragma unroll
        for (int r8 = 0; r8 < 8; ++r8) {
            const int row = rgrp * 8 + r8;
            float slt = SLT[row];
            float4 db = *(const float4*)(dec_b + cbase);
            float4 a;
            a.x = slt * db.x; a.y = slt * db.y; a.z = slt * db.z; a.w = slt * db.w;
#pragma unroll
            for (int k = 0; k < 4; ++k) {
                int   si = SWi[row][k];
                float sv = SWv[row][k];
                float4 sb = *(const float4*)(sbank + (size_t)si * DIM + cbase);
                fma4(a, sv, sb);
            }
            acc[r8] = a;
        }
#pragma unroll 1
        for (int jh = 0; jh < 2; ++jh) {
            __syncthreads();   // prior Wd/Pl readers done before restage
#pragma unroll
            for (int i = 0; i < 8; ++i) {
                int e = t + 256 * i;
                int jr = e >> 6, c4 = e & 63;
                *(float4*)&Wd[jr][4 * c4] =
                    *(const float4*)(dec_w + (size_t)(32 * jh + jr) * DIM + dc * 256 + 4 * c4);
            }
            __syncthreads();
#pragma unroll 4
            for (int j2 = 0; j2 < 32; ++j2) {
                float4 wv4 = *(const float4*)&Wd[j2][4 * col4];
#pragma unroll
                for (int r8 = 0; r8 < 8; ++r8) {
                    float z = Zl[rgrp * 8 + r8][32 * jh + j2];
                    fma4(acc[r8], z, wv4);
                }
            }
        }
#pragma unroll
        for (int r8 = 0; r8 < 8; ++r8) {
            const int row = rgrp * 8 + r8;
            *(float4*)(out + (size_t)(row0 + row) * DIM + cbase) = acc[r8];
        }
    }
}

// ---------------- launcher ----------------

extern "C" void kernel_launch(void* const* d_in, const int* in_sizes, int n_in,
                              void* d_out, int out_size, void* d_ws, size_t ws_size,
                              hipStream_t stream) {
    const float* query = (const float*)d_in[0];
    const float* sbank = (const float*)d_in[1];
    const float* lbank = (const float*)d_in[2];
    const float* dec_w = (const float*)d_in[3];
    const float* dec_b = (const float*)d_in[4];
    const float* q_w   = (const float*)d_in[5];
    const float* q_b   = (const float*)d_in[6];
    const float* sq_w  = (const float*)d_in[7];
    const float* sq_b  = (const float*)d_in[8];
    float* out = (float*)d_out;

    char* ws = (char*)d_ws;
    double* W2d    = (double*)(ws);             // [0, 262144)
    double* sconst = (double*)(ws + 262144);    // [262144, 262400)

    prep_w2 <<<dim3(128), dim3(256), 0, stream>>>(sq_w, sbank, sq_b, W2d, sconst);
    hmb_main<<<dim3(BROWS / RPB), dim3(256), 0, stream>>>(
        query, q_w, q_b, W2d, sconst, lbank, dec_w, dec_b, sbank, out);
}